// Round 3
// baseline (1168.726 us; speedup 1.0000x reference)
//
#include <hip/hip_runtime.h>

typedef __attribute__((ext_vector_type(8))) short short8;
typedef __attribute__((ext_vector_type(4))) float f32x4;

#define NN 100000
#define NE 600000
#define RR 128
#define HH 256
#define HP 264       // H-tile LDS row stride (256 + 8 pad)
#define NB_SCAN 98   // ceil(NN/1024)

__device__ __forceinline__ unsigned short f2bf(float f) {
    unsigned u = __builtin_bit_cast(unsigned, f);
    u = (u + 0x7fffu + ((u >> 16) & 1u)) >> 16;   // RNE
    return (unsigned short)u;
}

// pack two f32 -> one dword of 2 bf16 (round-half-up), 3 VALU ops
__device__ __forceinline__ unsigned pkbf(float lo, float hi) {
    unsigned a = __builtin_bit_cast(unsigned, lo) + 0x8000u;
    unsigned b = __builtin_bit_cast(unsigned, hi) + 0x8000u;
    return __builtin_amdgcn_perm(b, a, 0x07060302);  // {b.hi16, a.hi16}
}
__device__ __forceinline__ short8 pack8(float4 a, float4 b) {
    uint4 u;
    u.x = pkbf(a.x, a.y); u.y = pkbf(a.z, a.w);
    u.z = pkbf(b.x, b.y); u.w = pkbf(b.z, b.w);
    return __builtin_bit_cast(short8, u);
}

__global__ __launch_bounds__(256) void transpose_cast(const float* __restrict__ src,
                                                      unsigned short* __restrict__ dst,
                                                      int K, int C) {
    int i = blockIdx.x * 256 + threadIdx.x;
    if (i >= K * C) return;
    int c = i / K, k = i - c * K;
    dst[i] = f2bf(src[k * C + c]);   // dst[c][k] = src[k][c]
}

// ---------------- CSR build ----------------
__global__ __launch_bounds__(256) void count_kernel(const int* __restrict__ esrc,
                                                    const int* __restrict__ edst,
                                                    int* __restrict__ cnt) {
    int i = blockIdx.x * 256 + threadIdx.x;
    if (i < NE) {
        atomicAdd(&cnt[esrc[i]], 1);
        atomicAdd(&cnt[edst[i]], 1);
    }
}

__global__ __launch_bounds__(1024) void scan_part(const int* __restrict__ cnt,
                                                  int* __restrict__ excl,
                                                  int* __restrict__ bsum) {
    __shared__ int wsum[16];
    const int tid = threadIdx.x;
    const int lane = tid & 63, w = tid >> 6;
    int i = blockIdx.x * 1024 + tid;
    int v = (i < NN) ? cnt[i] : 0;
    int s = v;
    #pragma unroll
    for (int d = 1; d < 64; d <<= 1) {
        int t = __shfl_up(s, d, 64);
        if (lane >= d) s += t;
    }
    if (lane == 63) wsum[w] = s;
    __syncthreads();
    if (w == 0) {
        int x = (lane < 16) ? wsum[lane] : 0;
        int sx = x;
        #pragma unroll
        for (int d = 1; d < 16; d <<= 1) {
            int t = __shfl_up(sx, d, 64);
            if (lane >= d) sx += t;
        }
        if (lane < 16) wsum[lane] = sx - x;          // exclusive wave offset
        if (lane == 15) bsum[blockIdx.x] = sx;       // block total
    }
    __syncthreads();
    if (i < NN) excl[i] = wsum[w] + (s - v);
}

__global__ void scan_tops(int* __restrict__ bsum, int* __restrict__ offs_nn) {
    if (threadIdx.x == 0) {
        int run = 0;
        for (int b = 0; b < NB_SCAN; ++b) { int t = bsum[b]; bsum[b] = run; run += t; }
        *offs_nn = run;   // offs[NN] = 2*NE
    }
}

__global__ __launch_bounds__(1024) void scan_add(int* __restrict__ offs,
                                                 const int* __restrict__ bsum,
                                                 int* __restrict__ cur) {
    int i = blockIdx.x * 1024 + threadIdx.x;
    if (i < NN) { int v = offs[i] + bsum[blockIdx.x]; offs[i] = v; cur[i] = v; }
}

__global__ __launch_bounds__(256) void fill_kernel(const int* __restrict__ esrc,
                                                   const int* __restrict__ edst,
                                                   int* __restrict__ cur,
                                                   int* __restrict__ adj) {
    int i = blockIdx.x * 256 + threadIdx.x;
    if (i < NE) {
        int p = atomicAdd(&cur[esrc[i]], 1);
        adj[p] = i;
        int q = atomicAdd(&cur[edst[i]], 1);
        adj[q] = i;
    }
}

// ---------------- edge kernel: direct-global B-fragments, LDS only for H ----------------
__global__ __launch_bounds__(256, 4) void edge_kernel(
    const float* __restrict__ node_rep, const float* __restrict__ edge_attr,
    const int* __restrict__ esrc, const int* __restrict__ edst,
    const unsigned short* __restrict__ w1t, const float* __restrict__ b1,
    const unsigned short* __restrict__ w2t, const float* __restrict__ b2,
    float* __restrict__ edge_out)
{
    __shared__ unsigned short Hbuf[64 * HP];
    const int tid = threadIdx.x;
    const int e0 = blockIdx.x * 64;
    const int lane = tid & 63, wave = tid >> 6;
    const int l15 = lane & 15, l4 = lane >> 4;
    const int hbase = wave * 64;

    // per-lane endpoint indices for the 4 e-tiles
    int si[4], di[4];
    #pragma unroll
    for (int et = 0; et < 4; ++et) {
        int e = e0 + et * 16 + l15;
        si[et] = esrc[e];
        di[et] = edst[e];
    }

    // GEMM1': D'[h][e] = sum_k W1T[h][k] * A[e][k], A read straight from global
    f32x4 acc[4][4] = {};
    #pragma unroll
    for (int seg = 0; seg < 3; ++seg) {
        const float* rp[4];
        #pragma unroll
        for (int et = 0; et < 4; ++et) {
            int e = e0 + et * 16 + l15;
            rp[et] = (seg == 0) ? edge_attr + (size_t)e * RR
                   : (seg == 1) ? node_rep + (size_t)si[et] * RR
                                : node_rep + (size_t)di[et] * RR;
        }
        #pragma unroll
        for (int k4 = 0; k4 < 4; ++k4) {
            const int kk = seg * 128 + k4 * 32;       // global k start of this step
            const int col = k4 * 32 + l4 * 8;         // within segment (floats)
            short8 bfr[4];
            #pragma unroll
            for (int et = 0; et < 4; ++et) {
                float4 va = *reinterpret_cast<const float4*>(rp[et] + col);
                float4 vb = *reinterpret_cast<const float4*>(rp[et] + col + 4);
                bfr[et] = pack8(va, vb);
            }
            #pragma unroll
            for (int ht = 0; ht < 4; ++ht) {
                short8 afr = *reinterpret_cast<const short8*>(
                    w1t + (size_t)(hbase + ht * 16 + l15) * 384 + kk + l4 * 8);
                #pragma unroll
                for (int et = 0; et < 4; ++et)
                    acc[ht][et] = __builtin_amdgcn_mfma_f32_16x16x32_bf16(afr, bfr[et], acc[ht][et], 0, 0, 0);
            }
        }
    }

    // bias + relu + bf16 -> Hbuf (each wave owns its 64-col slice; no race)
    #pragma unroll
    for (int ht = 0; ht < 4; ++ht) {
        const int h0 = hbase + ht * 16 + l4 * 4;
        float4 bb = *reinterpret_cast<const float4*>(b1 + h0);
        #pragma unroll
        for (int et = 0; et < 4; ++et) {
            int e = et * 16 + l15;
            float x0 = fmaxf(acc[ht][et][0] + bb.x, 0.f);
            float x1 = fmaxf(acc[ht][et][1] + bb.y, 0.f);
            float x2 = fmaxf(acc[ht][et][2] + bb.z, 0.f);
            float x3 = fmaxf(acc[ht][et][3] + bb.w, 0.f);
            uint2 u;
            u.x = pkbf(x0, x1);
            u.y = pkbf(x2, x3);
            *reinterpret_cast<uint2*>(&Hbuf[e * HP + h0]) = u;
        }
    }
    __syncthreads();

    // GEMM2': D2'[c][e] = sum_h W2T[c][h] * H[e][h]
    f32x4 acc2[2][4] = {};
    const int cbase = wave * 32;
    for (int kk = 0; kk < 256; kk += 32) {
        const int koff = kk + l4 * 8;
        short8 bfr[4];
        #pragma unroll
        for (int et = 0; et < 4; ++et)
            bfr[et] = *reinterpret_cast<const short8*>(&Hbuf[(et * 16 + l15) * HP + koff]);
        #pragma unroll
        for (int ct = 0; ct < 2; ++ct) {
            short8 afr = *reinterpret_cast<const short8*>(
                w2t + (size_t)(cbase + ct * 16 + l15) * 256 + koff);
            #pragma unroll
            for (int et = 0; et < 4; ++et)
                acc2[ct][et] = __builtin_amdgcn_mfma_f32_16x16x32_bf16(afr, bfr[et], acc2[ct][et], 0, 0, 0);
        }
    }

    // epilogue: bias + store edge_out
    #pragma unroll
    for (int ct = 0; ct < 2; ++ct) {
        const int c0 = cbase + ct * 16 + l4 * 4;
        float4 bb = *reinterpret_cast<const float4*>(b2 + c0);
        #pragma unroll
        for (int et = 0; et < 4; ++et) {
            int e = et * 16 + l15;
            float4 v;
            v.x = acc2[ct][et][0] + bb.x;
            v.y = acc2[ct][et][1] + bb.y;
            v.z = acc2[ct][et][2] + bb.z;
            v.w = acc2[ct][et][3] + bb.w;
            *reinterpret_cast<float4*>(edge_out + (size_t)(e0 + e) * RR + c0) = v;
        }
    }
}

// ---------------- node kernel: pull e2n via CSR + MLP -> node_out ----------------
__global__ __launch_bounds__(256) void node_kernel(
    const float* __restrict__ node_rep,
    const int* __restrict__ offs, const int* __restrict__ adj,
    const float* __restrict__ edge_out,
    const unsigned short* __restrict__ w1t, const float* __restrict__ b1,
    const unsigned short* __restrict__ w2t, const float* __restrict__ b2,
    float* __restrict__ out)
{
    __shared__ unsigned short Abuf[64 * HP];
    const int tid = threadIdx.x;
    const int n0 = blockIdx.x * 64;
    const int r = tid >> 2, q = tid & 3;       // row, quarter (32 floats each)
    const int n = n0 + r;

    // node_rep -> Abuf cols [q*32, q*32+32)
    {
        int nc = n < NN ? n : NN - 1;
        const f32x4* src = reinterpret_cast<const f32x4*>(node_rep + (size_t)nc * RR + q * 32);
        #pragma unroll
        for (int j = 0; j < 8; ++j) {
            f32x4 v = src[j];
            uint2 u;
            u.x = pkbf(v[0], v[1]);
            u.y = pkbf(v[2], v[3]);
            *reinterpret_cast<uint2*>(&Abuf[r * HP + q * 32 + (j << 2)]) = u;
        }
    }
    // e2n: f32 gather-sum of incident edge_out rows -> Abuf cols [128+q*32, ...)
    {
        f32x4 acc8[8] = {};
        if (n < NN) {
            const int pe = offs[n + 1];
            for (int p = offs[n]; p < pe; ++p) {
                int e = adj[p];
                const f32x4* src = reinterpret_cast<const f32x4*>(edge_out + (size_t)e * RR + q * 32);
                #pragma unroll
                for (int j = 0; j < 8; ++j) acc8[j] += src[j];
            }
        }
        #pragma unroll
        for (int j = 0; j < 8; ++j) {
            uint2 u;
            u.x = pkbf(acc8[j][0], acc8[j][1]);
            u.y = pkbf(acc8[j][2], acc8[j][3]);
            *reinterpret_cast<uint2*>(&Abuf[r * HP + 128 + q * 32 + (j << 2)]) = u;
        }
    }
    __syncthreads();

    const int lane = tid & 63, wave = tid >> 6;
    const int l15 = lane & 15, l4 = lane >> 4;
    const int hbase = wave * 64;

    f32x4 acc[4][4] = {};
    for (int kk = 0; kk < 256; kk += 32) {
        const int koff = kk + l4 * 8;
        short8 bfr[4];
        #pragma unroll
        for (int et = 0; et < 4; ++et)
            bfr[et] = *reinterpret_cast<const short8*>(&Abuf[(et * 16 + l15) * HP + koff]);
        #pragma unroll
        for (int ht = 0; ht < 4; ++ht) {
            short8 afr = *reinterpret_cast<const short8*>(w1t + (size_t)(hbase + ht * 16 + l15) * 256 + koff);
            #pragma unroll
            for (int et = 0; et < 4; ++et)
                acc[ht][et] = __builtin_amdgcn_mfma_f32_16x16x32_bf16(afr, bfr[et], acc[ht][et], 0, 0, 0);
        }
    }
    __syncthreads();

    unsigned short* Hbuf = Abuf;
    #pragma unroll
    for (int ht = 0; ht < 4; ++ht) {
        const int h0 = hbase + ht * 16 + l4 * 4;
        float4 bb = *reinterpret_cast<const float4*>(b1 + h0);
        #pragma unroll
        for (int et = 0; et < 4; ++et) {
            int e = et * 16 + l15;
            float x0 = fmaxf(acc[ht][et][0] + bb.x, 0.f);
            float x1 = fmaxf(acc[ht][et][1] + bb.y, 0.f);
            float x2 = fmaxf(acc[ht][et][2] + bb.z, 0.f);
            float x3 = fmaxf(acc[ht][et][3] + bb.w, 0.f);
            uint2 u;
            u.x = pkbf(x0, x1);
            u.y = pkbf(x2, x3);
            *reinterpret_cast<uint2*>(&Hbuf[e * HP + h0]) = u;
        }
    }
    __syncthreads();

    f32x4 acc2[2][4] = {};
    const int cbase = wave * 32;
    for (int kk = 0; kk < 256; kk += 32) {
        const int koff = kk + l4 * 8;
        short8 bfr[4];
        #pragma unroll
        for (int et = 0; et < 4; ++et)
            bfr[et] = *reinterpret_cast<const short8*>(&Hbuf[(et * 16 + l15) * HP + koff]);
        #pragma unroll
        for (int ct = 0; ct < 2; ++ct) {
            short8 afr = *reinterpret_cast<const short8*>(w2t + (size_t)(cbase + ct * 16 + l15) * 256 + koff);
            #pragma unroll
            for (int et = 0; et < 4; ++et)
                acc2[ct][et] = __builtin_amdgcn_mfma_f32_16x16x32_bf16(afr, bfr[et], acc2[ct][et], 0, 0, 0);
        }
    }

    #pragma unroll
    for (int ct = 0; ct < 2; ++ct) {
        const int c0 = cbase + ct * 16 + l4 * 4;
        float4 bb = *reinterpret_cast<const float4*>(b2 + c0);
        #pragma unroll
        for (int et = 0; et < 4; ++et) {
            int nn = n0 + et * 16 + l15;
            if (nn < NN) {
                float4 v;
                v.x = acc2[ct][et][0] + bb.x;
                v.y = acc2[ct][et][1] + bb.y;
                v.z = acc2[ct][et][2] + bb.z;
                v.w = acc2[ct][et][3] + bb.w;
                *reinterpret_cast<float4*>(out + (size_t)nn * RR + c0) = v;
            }
        }
    }
}

extern "C" void kernel_launch(void* const* d_in, const int* in_sizes, int n_in,
                              void* d_out, int out_size, void* d_ws, size_t ws_size,
                              hipStream_t stream) {
    const float* node_rep  = (const float*)d_in[0];
    const float* edge_attr = (const float*)d_in[1];
    const int*   esrc      = (const int*)d_in[2];
    const int*   edst      = (const int*)d_in[3];
    const float* W1e = (const float*)d_in[4];
    const float* b1e = (const float*)d_in[5];
    const float* W2e = (const float*)d_in[6];
    const float* b2e = (const float*)d_in[7];
    const float* W1n = (const float*)d_in[8];
    const float* b1n = (const float*)d_in[9];
    const float* W2n = (const float*)d_in[10];
    const float* b2n = (const float*)d_in[11];

    float* out      = (float*)d_out;
    float* node_out = out;                          // N*R
    float* edge_out = out + (size_t)NN * RR;        // E*R

    // workspace layout
    char* ws = (char*)d_ws;
    unsigned short* w1et = (unsigned short*)ws;                 // [256][384]
    unsigned short* w2et = w1et + 256 * 384;                    // [128][256]
    unsigned short* w1nt = w2et + 128 * 256;                    // [256][256]
    unsigned short* w2nt = w1nt + 256 * 256;                    // [128][256]
    int* cnt  = (int*)(ws + 458752);                            // [NN]  (also fill cursor)
    int* offs = (int*)(ws + 458752 + 400000);                   // [NN+1]
    int* adj  = (int*)(ws + 458752 + 400000 + 400008);          // [2*NE]
    int* bsum = (int*)(ws + 458752 + 400000 + 400008 + 4800000);// [NB_SCAN]

    hipMemsetAsync(cnt, 0, (size_t)NN * sizeof(int), stream);

    transpose_cast<<<(384 * 256 + 255) / 256, 256, 0, stream>>>(W1e, w1et, 384, 256);
    transpose_cast<<<(256 * 128 + 255) / 256, 256, 0, stream>>>(W2e, w2et, 256, 128);
    transpose_cast<<<(256 * 256 + 255) / 256, 256, 0, stream>>>(W1n, w1nt, 256, 256);
    transpose_cast<<<(256 * 128 + 255) / 256, 256, 0, stream>>>(W2n, w2nt, 256, 128);

    count_kernel<<<(NE + 255) / 256, 256, 0, stream>>>(esrc, edst, cnt);
    scan_part<<<NB_SCAN, 1024, 0, stream>>>(cnt, offs, bsum);
    scan_tops<<<1, 64, 0, stream>>>(bsum, offs + NN);
    scan_add<<<NB_SCAN, 1024, 0, stream>>>(offs, bsum, cnt);
    fill_kernel<<<(NE + 255) / 256, 256, 0, stream>>>(esrc, edst, cnt, adj);

    edge_kernel<<<NE / 64, 256, 0, stream>>>(node_rep, edge_attr, esrc, edst,
                                             w1et, b1e, w2et, b2e, edge_out);

    node_kernel<<<(NN + 63) / 64, 256, 0, stream>>>(node_rep, offs, adj, edge_out,
                                                    w1nt, b1n, w2nt, b2n, node_out);
}

// Round 4
// 822.165 us; speedup vs baseline: 1.4215x; 1.4215x over previous
//
#include <hip/hip_runtime.h>

typedef __attribute__((ext_vector_type(8))) short short8;
typedef __attribute__((ext_vector_type(4))) float f32x4;

#define NN 100000
#define NE 600000
#define RR 128
#define HH 256
#define AP 392       // edge A-tile LDS row stride (384 + 8 pad)
#define HP 264       // H-tile LDS row stride (256 + 8 pad)
#define NB_SCAN 98   // ceil(NN/1024)

__device__ __forceinline__ unsigned short f2bf(float f) {
    unsigned u = __builtin_bit_cast(unsigned, f);
    u = (u + 0x7fffu + ((u >> 16) & 1u)) >> 16;   // RNE
    return (unsigned short)u;
}

// pack two f32 -> one dword of 2 bf16 (round-half-up), 3 VALU ops
__device__ __forceinline__ unsigned pkbf(float lo, float hi) {
    unsigned a = __builtin_bit_cast(unsigned, lo) + 0x8000u;
    unsigned b = __builtin_bit_cast(unsigned, hi) + 0x8000u;
    return __builtin_amdgcn_perm(b, a, 0x07060302);  // {b.hi16, a.hi16}
}

__global__ __launch_bounds__(256) void transpose_cast(const float* __restrict__ src,
                                                      unsigned short* __restrict__ dst,
                                                      int K, int C) {
    int i = blockIdx.x * 256 + threadIdx.x;
    if (i >= K * C) return;
    int c = i / K, k = i - c * K;
    dst[i] = f2bf(src[k * C + c]);   // dst[c][k] = src[k][c]
}

// ---------------- CSR build ----------------
__global__ __launch_bounds__(256) void count_kernel(const int* __restrict__ esrc,
                                                    const int* __restrict__ edst,
                                                    int* __restrict__ cnt) {
    int i = blockIdx.x * 256 + threadIdx.x;
    if (i < NE) {
        atomicAdd(&cnt[esrc[i]], 1);
        atomicAdd(&cnt[edst[i]], 1);
    }
}

__global__ __launch_bounds__(1024) void scan_part(const int* __restrict__ cnt,
                                                  int* __restrict__ excl,
                                                  int* __restrict__ bsum) {
    __shared__ int wsum[16];
    const int tid = threadIdx.x;
    const int lane = tid & 63, w = tid >> 6;
    int i = blockIdx.x * 1024 + tid;
    int v = (i < NN) ? cnt[i] : 0;
    int s = v;
    #pragma unroll
    for (int d = 1; d < 64; d <<= 1) {
        int t = __shfl_up(s, d, 64);
        if (lane >= d) s += t;
    }
    if (lane == 63) wsum[w] = s;
    __syncthreads();
    if (w == 0) {
        int x = (lane < 16) ? wsum[lane] : 0;
        int sx = x;
        #pragma unroll
        for (int d = 1; d < 16; d <<= 1) {
            int t = __shfl_up(sx, d, 64);
            if (lane >= d) sx += t;
        }
        if (lane < 16) wsum[lane] = sx - x;          // exclusive wave offset
        if (lane == 15) bsum[blockIdx.x] = sx;       // block total
    }
    __syncthreads();
    if (i < NN) excl[i] = wsum[w] + (s - v);
}

__global__ void scan_tops(int* __restrict__ bsum, int* __restrict__ offs_nn) {
    if (threadIdx.x == 0) {
        int run = 0;
        for (int b = 0; b < NB_SCAN; ++b) { int t = bsum[b]; bsum[b] = run; run += t; }
        *offs_nn = run;   // offs[NN] = 2*NE
    }
}

__global__ __launch_bounds__(1024) void scan_add(int* __restrict__ offs,
                                                 const int* __restrict__ bsum,
                                                 int* __restrict__ cur) {
    int i = blockIdx.x * 1024 + threadIdx.x;
    if (i < NN) { int v = offs[i] + bsum[blockIdx.x]; offs[i] = v; cur[i] = v; }
}

__global__ __launch_bounds__(256) void fill_kernel(const int* __restrict__ esrc,
                                                   const int* __restrict__ edst,
                                                   int* __restrict__ cur,
                                                   int* __restrict__ adj) {
    int i = blockIdx.x * 256 + threadIdx.x;
    if (i < NE) {
        int p = atomicAdd(&cur[esrc[i]], 1);
        adj[p] = i;
        int q = atomicAdd(&cur[edst[i]], 1);
        adj[q] = i;
    }
}

// ---------------- edge kernel: staged gather + MLP, 8 waves ----------------
__global__ __launch_bounds__(512, 6) void edge_kernel(
    const float* __restrict__ node_rep, const float* __restrict__ edge_attr,
    const int* __restrict__ esrc, const int* __restrict__ edst,
    const unsigned short* __restrict__ w1t, const float* __restrict__ b1,
    const unsigned short* __restrict__ w2t, const float* __restrict__ b2,
    float* __restrict__ edge_out)
{
    __shared__ unsigned short Abuf[64 * AP];   // A-tile, later reused as H-tile
    __shared__ int sidx[64], didx[64];
    const int tid = threadIdx.x;
    const int e0 = blockIdx.x * 64;

    if (tid < 64) sidx[tid] = esrc[e0 + tid];
    else if (tid < 128) didx[tid - 64] = edst[e0 + tid - 64];
    __syncthreads();

    // gather [edge_attr | node_src | node_dst] -> bf16 LDS, 64 rows x 384
    for (int i = tid; i < 64 * 96; i += 512) {
        int row = i / 96;
        int c4 = i - row * 96;
        const float* p;
        if (c4 < 32)      p = edge_attr + (size_t)(e0 + row) * RR + (c4 << 2);
        else if (c4 < 64) p = node_rep + (size_t)sidx[row] * RR + ((c4 - 32) << 2);
        else              p = node_rep + (size_t)didx[row] * RR + ((c4 - 64) << 2);
        float4 v = *reinterpret_cast<const float4*>(p);
        uint2 u;
        u.x = pkbf(v.x, v.y);
        u.y = pkbf(v.z, v.w);
        *reinterpret_cast<uint2*>(&Abuf[row * AP + (c4 << 2)]) = u;
    }
    __syncthreads();

    const int lane = tid & 63, wave = tid >> 6;
    const int l15 = lane & 15, l4 = lane >> 4;
    const int hbase = wave * 32;

    // GEMM1': D'[h][e] = sum_k W1T[h][k] * A[e][k]   (2 ht-tiles per wave)
    f32x4 acc[2][4] = {};
    for (int kk = 0; kk < 384; kk += 32) {
        const int koff = kk + l4 * 8;
        short8 bfr[4];
        #pragma unroll
        for (int et = 0; et < 4; ++et)
            bfr[et] = *reinterpret_cast<const short8*>(&Abuf[(et * 16 + l15) * AP + koff]);
        #pragma unroll
        for (int ht = 0; ht < 2; ++ht) {
            short8 afr = *reinterpret_cast<const short8*>(
                w1t + (size_t)(hbase + ht * 16 + l15) * 384 + koff);
            #pragma unroll
            for (int et = 0; et < 4; ++et)
                acc[ht][et] = __builtin_amdgcn_mfma_f32_16x16x32_bf16(afr, bfr[et], acc[ht][et], 0, 0, 0);
        }
    }
    __syncthreads();   // everyone done reading Abuf

    // bias + relu + bf16, store H[e][h] into reused LDS (stride HP)
    unsigned short* Hbuf = Abuf;
    #pragma unroll
    for (int ht = 0; ht < 2; ++ht) {
        const int h0 = hbase + ht * 16 + l4 * 4;
        float4 bb = *reinterpret_cast<const float4*>(b1 + h0);
        #pragma unroll
        for (int et = 0; et < 4; ++et) {
            int e = et * 16 + l15;
            float x0 = fmaxf(acc[ht][et][0] + bb.x, 0.f);
            float x1 = fmaxf(acc[ht][et][1] + bb.y, 0.f);
            float x2 = fmaxf(acc[ht][et][2] + bb.z, 0.f);
            float x3 = fmaxf(acc[ht][et][3] + bb.w, 0.f);
            uint2 u;
            u.x = pkbf(x0, x1);
            u.y = pkbf(x2, x3);
            *reinterpret_cast<uint2*>(&Hbuf[e * HP + h0]) = u;
        }
    }
    __syncthreads();

    // GEMM2': D2'[c][e] = sum_h W2T[c][h] * H[e][h]   (1 ct-tile per wave)
    f32x4 acc2[4] = {};
    const int cbase = wave * 16;
    for (int kk = 0; kk < 256; kk += 32) {
        const int koff = kk + l4 * 8;
        short8 afr = *reinterpret_cast<const short8*>(
            w2t + (size_t)(cbase + l15) * 256 + koff);
        #pragma unroll
        for (int et = 0; et < 4; ++et) {
            short8 bfr = *reinterpret_cast<const short8*>(&Hbuf[(et * 16 + l15) * HP + koff]);
            acc2[et] = __builtin_amdgcn_mfma_f32_16x16x32_bf16(afr, bfr, acc2[et], 0, 0, 0);
        }
    }

    // epilogue: bias + store edge_out
    {
        const int c0 = cbase + l4 * 4;
        float4 bb = *reinterpret_cast<const float4*>(b2 + c0);
        #pragma unroll
        for (int et = 0; et < 4; ++et) {
            int e = et * 16 + l15;
            float4 v;
            v.x = acc2[et][0] + bb.x;
            v.y = acc2[et][1] + bb.y;
            v.z = acc2[et][2] + bb.z;
            v.w = acc2[et][3] + bb.w;
            *reinterpret_cast<float4*>(edge_out + (size_t)(e0 + e) * RR + c0) = v;
        }
    }
}

// ---------------- node kernel: pull e2n via CSR + MLP -> node_out ----------------
__global__ __launch_bounds__(256) void node_kernel(
    const float* __restrict__ node_rep,
    const int* __restrict__ offs, const int* __restrict__ adj,
    const float* __restrict__ edge_out,
    const unsigned short* __restrict__ w1t, const float* __restrict__ b1,
    const unsigned short* __restrict__ w2t, const float* __restrict__ b2,
    float* __restrict__ out)
{
    __shared__ unsigned short Abuf[64 * HP];
    const int tid = threadIdx.x;
    const int n0 = blockIdx.x * 64;
    const int r = tid >> 2, q = tid & 3;       // row, quarter (32 floats each)
    const int n = n0 + r;

    // node_rep -> Abuf cols [q*32, q*32+32)
    {
        int nc = n < NN ? n : NN - 1;
        const f32x4* src = reinterpret_cast<const f32x4*>(node_rep + (size_t)nc * RR + q * 32);
        #pragma unroll
        for (int j = 0; j < 8; ++j) {
            f32x4 v = src[j];
            uint2 u;
            u.x = pkbf(v[0], v[1]);
            u.y = pkbf(v[2], v[3]);
            *reinterpret_cast<uint2*>(&Abuf[r * HP + q * 32 + (j << 2)]) = u;
        }
    }
    // e2n: f32 gather-sum of incident edge_out rows -> Abuf cols [128+q*32, ...)
    {
        f32x4 acc8[8] = {};
        if (n < NN) {
            const int pe = offs[n + 1];
            for (int p = offs[n]; p < pe; ++p) {
                int e = adj[p];
                const f32x4* src = reinterpret_cast<const f32x4*>(edge_out + (size_t)e * RR + q * 32);
                #pragma unroll
                for (int j = 0; j < 8; ++j) acc8[j] += src[j];
            }
        }
        #pragma unroll
        for (int j = 0; j < 8; ++j) {
            uint2 u;
            u.x = pkbf(acc8[j][0], acc8[j][1]);
            u.y = pkbf(acc8[j][2], acc8[j][3]);
            *reinterpret_cast<uint2*>(&Abuf[r * HP + 128 + q * 32 + (j << 2)]) = u;
        }
    }
    __syncthreads();

    const int lane = tid & 63, wave = tid >> 6;
    const int l15 = lane & 15, l4 = lane >> 4;
    const int hbase = wave * 64;

    f32x4 acc[4][4] = {};
    for (int kk = 0; kk < 256; kk += 32) {
        const int koff = kk + l4 * 8;
        short8 bfr[4];
        #pragma unroll
        for (int et = 0; et < 4; ++et)
            bfr[et] = *reinterpret_cast<const short8*>(&Abuf[(et * 16 + l15) * HP + koff]);
        #pragma unroll
        for (int ht = 0; ht < 4; ++ht) {
            short8 afr = *reinterpret_cast<const short8*>(w1t + (size_t)(hbase + ht * 16 + l15) * 256 + koff);
            #pragma unroll
            for (int et = 0; et < 4; ++et)
                acc[ht][et] = __builtin_amdgcn_mfma_f32_16x16x32_bf16(afr, bfr[et], acc[ht][et], 0, 0, 0);
        }
    }
    __syncthreads();

    unsigned short* Hbuf = Abuf;
    #pragma unroll
    for (int ht = 0; ht < 4; ++ht) {
        const int h0 = hbase + ht * 16 + l4 * 4;
        float4 bb = *reinterpret_cast<const float4*>(b1 + h0);
        #pragma unroll
        for (int et = 0; et < 4; ++et) {
            int e = et * 16 + l15;
            float x0 = fmaxf(acc[ht][et][0] + bb.x, 0.f);
            float x1 = fmaxf(acc[ht][et][1] + bb.y, 0.f);
            float x2 = fmaxf(acc[ht][et][2] + bb.z, 0.f);
            float x3 = fmaxf(acc[ht][et][3] + bb.w, 0.f);
            uint2 u;
            u.x = pkbf(x0, x1);
            u.y = pkbf(x2, x3);
            *reinterpret_cast<uint2*>(&Hbuf[e * HP + h0]) = u;
        }
    }
    __syncthreads();

    f32x4 acc2[2][4] = {};
    const int cbase = wave * 32;
    for (int kk = 0; kk < 256; kk += 32) {
        const int koff = kk + l4 * 8;
        short8 bfr[4];
        #pragma unroll
        for (int et = 0; et < 4; ++et)
            bfr[et] = *reinterpret_cast<const short8*>(&Hbuf[(et * 16 + l15) * HP + koff]);
        #pragma unroll
        for (int ct = 0; ct < 2; ++ct) {
            short8 afr = *reinterpret_cast<const short8*>(w2t + (size_t)(cbase + ct * 16 + l15) * 256 + koff);
            #pragma unroll
            for (int et = 0; et < 4; ++et)
                acc2[ct][et] = __builtin_amdgcn_mfma_f32_16x16x32_bf16(afr, bfr[et], acc2[ct][et], 0, 0, 0);
        }
    }

    #pragma unroll
    for (int ct = 0; ct < 2; ++ct) {
        const int c0 = cbase + ct * 16 + l4 * 4;
        float4 bb = *reinterpret_cast<const float4*>(b2 + c0);
        #pragma unroll
        for (int et = 0; et < 4; ++et) {
            int nn = n0 + et * 16 + l15;
            if (nn < NN) {
                float4 v;
                v.x = acc2[ct][et][0] + bb.x;
                v.y = acc2[ct][et][1] + bb.y;
                v.z = acc2[ct][et][2] + bb.z;
                v.w = acc2[ct][et][3] + bb.w;
                *reinterpret_cast<float4*>(out + (size_t)nn * RR + c0) = v;
            }
        }
    }
}

extern "C" void kernel_launch(void* const* d_in, const int* in_sizes, int n_in,
                              void* d_out, int out_size, void* d_ws, size_t ws_size,
                              hipStream_t stream) {
    const float* node_rep  = (const float*)d_in[0];
    const float* edge_attr = (const float*)d_in[1];
    const int*   esrc      = (const int*)d_in[2];
    const int*   edst      = (const int*)d_in[3];
    const float* W1e = (const float*)d_in[4];
    const float* b1e = (const float*)d_in[5];
    const float* W2e = (const float*)d_in[6];
    const float* b2e = (const float*)d_in[7];
    const float* W1n = (const float*)d_in[8];
    const float* b1n = (const float*)d_in[9];
    const float* W2n = (const float*)d_in[10];
    const float* b2n = (const float*)d_in[11];

    float* out      = (float*)d_out;
    float* node_out = out;                          // N*R
    float* edge_out = out + (size_t)NN * RR;        // E*R

    // workspace layout
    char* ws = (char*)d_ws;
    unsigned short* w1et = (unsigned short*)ws;                 // [256][384]
    unsigned short* w2et = w1et + 256 * 384;                    // [128][256]
    unsigned short* w1nt = w2et + 128 * 256;                    // [256][256]
    unsigned short* w2nt = w1nt + 256 * 256;                    // [128][256]
    int* cnt  = (int*)(ws + 458752);                            // [NN]  (also fill cursor)
    int* offs = (int*)(ws + 458752 + 400000);                   // [NN+1]
    int* adj  = (int*)(ws + 458752 + 400000 + 400008);          // [2*NE]
    int* bsum = (int*)(ws + 458752 + 400000 + 400008 + 4800000);// [NB_SCAN]

    hipMemsetAsync(cnt, 0, (size_t)NN * sizeof(int), stream);

    transpose_cast<<<(384 * 256 + 255) / 256, 256, 0, stream>>>(W1e, w1et, 384, 256);
    transpose_cast<<<(256 * 128 + 255) / 256, 256, 0, stream>>>(W2e, w2et, 256, 128);
    transpose_cast<<<(256 * 256 + 255) / 256, 256, 0, stream>>>(W1n, w1nt, 256, 256);
    transpose_cast<<<(256 * 128 + 255) / 256, 256, 0, stream>>>(W2n, w2nt, 256, 128);

    count_kernel<<<(NE + 255) / 256, 256, 0, stream>>>(esrc, edst, cnt);
    scan_part<<<NB_SCAN, 1024, 0, stream>>>(cnt, offs, bsum);
    scan_tops<<<1, 64, 0, stream>>>(bsum, offs + NN);
    scan_add<<<NB_SCAN, 1024, 0, stream>>>(offs, bsum, cnt);
    fill_kernel<<<(NE + 255) / 256, 256, 0, stream>>>(esrc, edst, cnt, adj);

    edge_kernel<<<NE / 64, 512, 0, stream>>>(node_rep, edge_attr, esrc, edst,
                                             w1et, b1e, w2et, b2e, edge_out);

    node_kernel<<<(NN + 63) / 64, 256, 0, stream>>>(node_rep, offs, adj, edge_out,
                                                    w1nt, b1n, w2nt, b2n, node_out);
}

// Round 5
// 749.583 us; speedup vs baseline: 1.5592x; 1.0968x over previous
//
#include <hip/hip_runtime.h>

typedef __attribute__((ext_vector_type(8))) short short8;
typedef __attribute__((ext_vector_type(4))) float f32x4;

#define NN 100000
#define NE 600000
#define RR 128
#define HH 256
#define NB_SCAN 98   // ceil(NN/1024)

__device__ __forceinline__ unsigned short f2bf(float f) {
    unsigned u = __builtin_bit_cast(unsigned, f);
    u = (u + 0x7fffu + ((u >> 16) & 1u)) >> 16;   // RNE
    return (unsigned short)u;
}

// pack two f32 -> one dword of 2 bf16 (round-half-up), 3 VALU ops
__device__ __forceinline__ unsigned pkbf(float lo, float hi) {
    unsigned a = __builtin_bit_cast(unsigned, lo) + 0x8000u;
    unsigned b = __builtin_bit_cast(unsigned, hi) + 0x8000u;
    return __builtin_amdgcn_perm(b, a, 0x07060302);  // {b.hi16, a.hi16}
}

// LDS XOR swizzle: spread 16B blocks of a row across bank groups
__device__ __forceinline__ int swz(int byteoff, int row) {
    return byteoff ^ ((row & 7) << 4);
}

__global__ __launch_bounds__(256) void transpose_cast(const float* __restrict__ src,
                                                      unsigned short* __restrict__ dst,
                                                      int K, int C) {
    int i = blockIdx.x * 256 + threadIdx.x;
    if (i >= K * C) return;
    int c = i / K, k = i - c * K;
    dst[i] = f2bf(src[k * C + c]);   // dst[c][k] = src[k][c]
}

// ---------------- CSR build ----------------
__global__ __launch_bounds__(256) void count_kernel(const int* __restrict__ esrc,
                                                    const int* __restrict__ edst,
                                                    int* __restrict__ cnt) {
    int i = blockIdx.x * 256 + threadIdx.x;
    if (i < NE) {
        atomicAdd(&cnt[esrc[i]], 1);
        atomicAdd(&cnt[edst[i]], 1);
    }
}

__global__ __launch_bounds__(1024) void scan_part(const int* __restrict__ cnt,
                                                  int* __restrict__ excl,
                                                  int* __restrict__ bsum) {
    __shared__ int wsum[16];
    const int tid = threadIdx.x;
    const int lane = tid & 63, w = tid >> 6;
    int i = blockIdx.x * 1024 + tid;
    int v = (i < NN) ? cnt[i] : 0;
    int s = v;
    #pragma unroll
    for (int d = 1; d < 64; d <<= 1) {
        int t = __shfl_up(s, d, 64);
        if (lane >= d) s += t;
    }
    if (lane == 63) wsum[w] = s;
    __syncthreads();
    if (w == 0) {
        int x = (lane < 16) ? wsum[lane] : 0;
        int sx = x;
        #pragma unroll
        for (int d = 1; d < 16; d <<= 1) {
            int t = __shfl_up(sx, d, 64);
            if (lane >= d) sx += t;
        }
        if (lane < 16) wsum[lane] = sx - x;          // exclusive wave offset
        if (lane == 15) bsum[blockIdx.x] = sx;       // block total
    }
    __syncthreads();
    if (i < NN) excl[i] = wsum[w] + (s - v);
}

__global__ void scan_tops(int* __restrict__ bsum, int* __restrict__ offs_nn) {
    if (threadIdx.x == 0) {
        int run = 0;
        for (int b = 0; b < NB_SCAN; ++b) { int t = bsum[b]; bsum[b] = run; run += t; }
        *offs_nn = run;   // offs[NN] = 2*NE
    }
}

__global__ __launch_bounds__(1024) void scan_add(int* __restrict__ offs,
                                                 const int* __restrict__ bsum,
                                                 int* __restrict__ cur) {
    int i = blockIdx.x * 1024 + threadIdx.x;
    if (i < NN) { int v = offs[i] + bsum[blockIdx.x]; offs[i] = v; cur[i] = v; }
}

__global__ __launch_bounds__(256) void fill_kernel(const int* __restrict__ esrc,
                                                   const int* __restrict__ edst,
                                                   int* __restrict__ cur,
                                                   int* __restrict__ adj) {
    int i = blockIdx.x * 256 + threadIdx.x;
    if (i < NE) {
        int p = atomicAdd(&cur[esrc[i]], 1);
        adj[p] = i;
        int q = atomicAdd(&cur[edst[i]], 1);
        adj[q] = i;
    }
}

// ---------------- edge kernel: segment-pipelined staging + MLP ----------------
// A-tile: 64 rows x 384 bf16, row stride 768B, XOR-swizzled. H aliases (stride 512B).
__global__ __launch_bounds__(512, 5) void edge_kernel(
    const float* __restrict__ node_rep, const float* __restrict__ edge_attr,
    const int* __restrict__ esrc, const int* __restrict__ edst,
    const unsigned short* __restrict__ w1t, const float* __restrict__ b1,
    const unsigned short* __restrict__ w2t, const float* __restrict__ b2,
    float* __restrict__ edge_out)
{
    __shared__ char Abuf[64 * 768];
    const int tid = threadIdx.x;
    const int e0 = blockIdx.x * 64;
    const int lane = tid & 63, wave = tid >> 6;
    const int l15 = lane & 15, l4 = lane >> 4;
    const int hbase = wave * 32;

    // per-wave full endpoint index copies (lane r holds index of edge e0+r)
    const int sv = esrc[e0 + lane];
    const int dv = edst[e0 + lane];

    // staging geometry: idx = tid + j*512 over 64 rows x 32 col4; row=idx>>5, c4=idx&31
    const int c4 = tid & 31;
    const int row_b = tid >> 5;           // base row (add j*16)

    float4 ga[4];

    // ---- stage segA (edge_attr, els 0..127) ----
    #pragma unroll
    for (int j = 0; j < 4; ++j) {
        int row = row_b + j * 16;
        ga[j] = *reinterpret_cast<const float4*>(edge_attr + (size_t)(e0 + row) * RR + c4 * 4);
    }
    #pragma unroll
    for (int j = 0; j < 4; ++j) {
        int row = row_b + j * 16;
        uint2 u; u.x = pkbf(ga[j].x, ga[j].y); u.y = pkbf(ga[j].z, ga[j].w);
        *reinterpret_cast<uint2*>(&Abuf[swz(row * 768 + c4 * 8, row)]) = u;
    }
    __syncthreads();   // segA ready

    f32x4 acc[2][4] = {};

    // ---- issue segB loads (src nodes), then GEMM1 ksteps 0-3 on segA ----
    #pragma unroll
    for (int j = 0; j < 4; ++j) {
        int row = row_b + j * 16;
        int ns = __shfl(sv, row);
        ga[j] = *reinterpret_cast<const float4*>(node_rep + (size_t)ns * RR + c4 * 4);
    }
    #pragma unroll
    for (int kk = 0; kk < 4; ++kk) {
        const int koel = kk * 32 + l4 * 8;
        short8 bfr[4];
        #pragma unroll
        for (int et = 0; et < 4; ++et) {
            int rw = et * 16 + l15;
            bfr[et] = *reinterpret_cast<const short8*>(&Abuf[swz(rw * 768 + koel * 2, rw)]);
        }
        #pragma unroll
        for (int ht = 0; ht < 2; ++ht) {
            short8 afr = *reinterpret_cast<const short8*>(
                w1t + (size_t)(hbase + ht * 16 + l15) * 384 + koel);
            #pragma unroll
            for (int et = 0; et < 4; ++et)
                acc[ht][et] = __builtin_amdgcn_mfma_f32_16x16x32_bf16(afr, bfr[et], acc[ht][et], 0, 0, 0);
        }
    }
    #pragma unroll
    for (int j = 0; j < 4; ++j) {
        int row = row_b + j * 16;
        uint2 u; u.x = pkbf(ga[j].x, ga[j].y); u.y = pkbf(ga[j].z, ga[j].w);
        *reinterpret_cast<uint2*>(&Abuf[swz(row * 768 + 256 + c4 * 8, row)]) = u;
    }
    __syncthreads();   // segB ready

    // ---- issue segC loads (dst nodes), then GEMM1 ksteps 4-7 on segB ----
    #pragma unroll
    for (int j = 0; j < 4; ++j) {
        int row = row_b + j * 16;
        int nd = __shfl(dv, row);
        ga[j] = *reinterpret_cast<const float4*>(node_rep + (size_t)nd * RR + c4 * 4);
    }
    #pragma unroll
    for (int kk = 4; kk < 8; ++kk) {
        const int koel = kk * 32 + l4 * 8;
        short8 bfr[4];
        #pragma unroll
        for (int et = 0; et < 4; ++et) {
            int rw = et * 16 + l15;
            bfr[et] = *reinterpret_cast<const short8*>(&Abuf[swz(rw * 768 + koel * 2, rw)]);
        }
        #pragma unroll
        for (int ht = 0; ht < 2; ++ht) {
            short8 afr = *reinterpret_cast<const short8*>(
                w1t + (size_t)(hbase + ht * 16 + l15) * 384 + koel);
            #pragma unroll
            for (int et = 0; et < 4; ++et)
                acc[ht][et] = __builtin_amdgcn_mfma_f32_16x16x32_bf16(afr, bfr[et], acc[ht][et], 0, 0, 0);
        }
    }
    #pragma unroll
    for (int j = 0; j < 4; ++j) {
        int row = row_b + j * 16;
        uint2 u; u.x = pkbf(ga[j].x, ga[j].y); u.y = pkbf(ga[j].z, ga[j].w);
        *reinterpret_cast<uint2*>(&Abuf[swz(row * 768 + 512 + c4 * 8, row)]) = u;
    }
    __syncthreads();   // segC ready

    // ---- GEMM1 ksteps 8-11 on segC ----
    #pragma unroll
    for (int kk = 8; kk < 12; ++kk) {
        const int koel = kk * 32 + l4 * 8;
        short8 bfr[4];
        #pragma unroll
        for (int et = 0; et < 4; ++et) {
            int rw = et * 16 + l15;
            bfr[et] = *reinterpret_cast<const short8*>(&Abuf[swz(rw * 768 + koel * 2, rw)]);
        }
        #pragma unroll
        for (int ht = 0; ht < 2; ++ht) {
            short8 afr = *reinterpret_cast<const short8*>(
                w1t + (size_t)(hbase + ht * 16 + l15) * 384 + koel);
            #pragma unroll
            for (int et = 0; et < 4; ++et)
                acc[ht][et] = __builtin_amdgcn_mfma_f32_16x16x32_bf16(afr, bfr[et], acc[ht][et], 0, 0, 0);
        }
    }
    __syncthreads();   // all A reads done; safe to alias H into Abuf

    // ---- H = relu(acc + b1) -> bf16 LDS (row stride 512B, swizzled) ----
    #pragma unroll
    for (int ht = 0; ht < 2; ++ht) {
        const int h0 = hbase + ht * 16 + l4 * 4;
        float4 bb = *reinterpret_cast<const float4*>(b1 + h0);
        #pragma unroll
        for (int et = 0; et < 4; ++et) {
            int e = et * 16 + l15;
            float x0 = fmaxf(acc[ht][et][0] + bb.x, 0.f);
            float x1 = fmaxf(acc[ht][et][1] + bb.y, 0.f);
            float x2 = fmaxf(acc[ht][et][2] + bb.z, 0.f);
            float x3 = fmaxf(acc[ht][et][3] + bb.w, 0.f);
            uint2 u; u.x = pkbf(x0, x1); u.y = pkbf(x2, x3);
            *reinterpret_cast<uint2*>(&Abuf[swz(e * 512 + h0 * 2, e)]) = u;
        }
    }
    __syncthreads();   // H ready

    // ---- GEMM2': D2'[c][e] = sum_h W2T[c][h] * H[e][h] (1 ct-tile per wave) ----
    f32x4 acc2[4] = {};
    const int cbase = wave * 16;
    #pragma unroll
    for (int kk = 0; kk < 256; kk += 32) {
        const int koel = kk + l4 * 8;
        short8 afr = *reinterpret_cast<const short8*>(
            w2t + (size_t)(cbase + l15) * 256 + koel);
        #pragma unroll
        for (int et = 0; et < 4; ++et) {
            int rw = et * 16 + l15;
            short8 bfr = *reinterpret_cast<const short8*>(&Abuf[swz(rw * 512 + koel * 2, rw)]);
            acc2[et] = __builtin_amdgcn_mfma_f32_16x16x32_bf16(afr, bfr, acc2[et], 0, 0, 0);
        }
    }

    // ---- epilogue: bias + store edge_out ----
    {
        const int c0 = cbase + l4 * 4;
        float4 bb = *reinterpret_cast<const float4*>(b2 + c0);
        #pragma unroll
        for (int et = 0; et < 4; ++et) {
            int e = et * 16 + l15;
            float4 v;
            v.x = acc2[et][0] + bb.x;
            v.y = acc2[et][1] + bb.y;
            v.z = acc2[et][2] + bb.z;
            v.w = acc2[et][3] + bb.w;
            *reinterpret_cast<float4*>(edge_out + (size_t)(e0 + e) * RR + c0) = v;
        }
    }
}

// ---------------- node kernel: unrolled CSR pull + MLP -> node_out ----------------
__global__ __launch_bounds__(512, 5) void node_kernel(
    const float* __restrict__ node_rep,
    const int* __restrict__ offs, const int* __restrict__ adj,
    const float* __restrict__ edge_out,
    const unsigned short* __restrict__ w1t, const float* __restrict__ b1,
    const unsigned short* __restrict__ w2t, const float* __restrict__ b2,
    float* __restrict__ out)
{
    __shared__ char Abuf[64 * 512];   // A-tile (256 bf16/row); H aliases after GEMM1
    const int tid = threadIdx.x;
    const int n0 = blockIdx.x * 64;
    const int r = tid >> 3, t8 = tid & 7;     // 8 threads/row, 16 floats each
    const int n = n0 + r;
    const int nc = (n < NN) ? n : NN - 1;

    // node_rep -> A cols [t8*16, +16)
    {
        const f32x4* src = reinterpret_cast<const f32x4*>(node_rep + (size_t)nc * RR + t8 * 16);
        f32x4 v0 = src[0], v1 = src[1], v2 = src[2], v3 = src[3];
        uint2 u;
        int b = r * 512 + t8 * 32;
        u.x = pkbf(v0[0], v0[1]); u.y = pkbf(v0[2], v0[3]);
        *reinterpret_cast<uint2*>(&Abuf[swz(b, r)]) = u;
        u.x = pkbf(v1[0], v1[1]); u.y = pkbf(v1[2], v1[3]);
        *reinterpret_cast<uint2*>(&Abuf[swz(b + 8, r)]) = u;
        u.x = pkbf(v2[0], v2[1]); u.y = pkbf(v2[2], v2[3]);
        *reinterpret_cast<uint2*>(&Abuf[swz(b + 16, r)]) = u;
        u.x = pkbf(v3[0], v3[1]); u.y = pkbf(v3[2], v3[3]);
        *reinterpret_cast<uint2*>(&Abuf[swz(b + 24, r)]) = u;
    }
    // e2n: f32 gather-sum (4-way unrolled for MLP) -> A cols [128+t8*16, +16)
    {
        f32x4 a0 = {}, a1 = {}, a2 = {}, a3 = {};
        if (n < NN) {
            int p = offs[n];
            const int pe = offs[n + 1];
            for (; p + 3 < pe; p += 4) {
                int ea = adj[p], eb = adj[p + 1], ec = adj[p + 2], ed = adj[p + 3];
                const f32x4* ra = reinterpret_cast<const f32x4*>(edge_out + (size_t)ea * RR + t8 * 16);
                const f32x4* rb = reinterpret_cast<const f32x4*>(edge_out + (size_t)eb * RR + t8 * 16);
                const f32x4* rc = reinterpret_cast<const f32x4*>(edge_out + (size_t)ec * RR + t8 * 16);
                const f32x4* rd = reinterpret_cast<const f32x4*>(edge_out + (size_t)ed * RR + t8 * 16);
                f32x4 x0 = ra[0], x1 = ra[1], x2 = ra[2], x3 = ra[3];
                f32x4 y0 = rb[0], y1 = rb[1], y2 = rb[2], y3 = rb[3];
                f32x4 z0 = rc[0], z1 = rc[1], z2 = rc[2], z3 = rc[3];
                f32x4 w0 = rd[0], w1 = rd[1], w2 = rd[2], w3 = rd[3];
                a0 += x0; a1 += x1; a2 += x2; a3 += x3;
                a0 += y0; a1 += y1; a2 += y2; a3 += y3;
                a0 += z0; a1 += z1; a2 += z2; a3 += z3;
                a0 += w0; a1 += w1; a2 += w2; a3 += w3;
            }
            for (; p < pe; ++p) {
                int e = adj[p];
                const f32x4* rr = reinterpret_cast<const f32x4*>(edge_out + (size_t)e * RR + t8 * 16);
                a0 += rr[0]; a1 += rr[1]; a2 += rr[2]; a3 += rr[3];
            }
        }
        uint2 u;
        int b = r * 512 + 256 + t8 * 32;
        u.x = pkbf(a0[0], a0[1]); u.y = pkbf(a0[2], a0[3]);
        *reinterpret_cast<uint2*>(&Abuf[swz(b, r)]) = u;
        u.x = pkbf(a1[0], a1[1]); u.y = pkbf(a1[2], a1[3]);
        *reinterpret_cast<uint2*>(&Abuf[swz(b + 8, r)]) = u;
        u.x = pkbf(a2[0], a2[1]); u.y = pkbf(a2[2], a2[3]);
        *reinterpret_cast<uint2*>(&Abuf[swz(b + 16, r)]) = u;
        u.x = pkbf(a3[0], a3[1]); u.y = pkbf(a3[2], a3[3]);
        *reinterpret_cast<uint2*>(&Abuf[swz(b + 24, r)]) = u;
    }
    __syncthreads();

    const int lane = tid & 63, wave = tid >> 6;
    const int l15 = lane & 15, l4 = lane >> 4;
    const int hbase = wave * 32;

    // GEMM1: k = 256
    f32x4 acc[2][4] = {};
    #pragma unroll
    for (int kk = 0; kk < 8; ++kk) {
        const int koel = kk * 32 + l4 * 8;
        short8 bfr[4];
        #pragma unroll
        for (int et = 0; et < 4; ++et) {
            int rw = et * 16 + l15;
            bfr[et] = *reinterpret_cast<const short8*>(&Abuf[swz(rw * 512 + koel * 2, rw)]);
        }
        #pragma unroll
        for (int ht = 0; ht < 2; ++ht) {
            short8 afr = *reinterpret_cast<const short8*>(
                w1t + (size_t)(hbase + ht * 16 + l15) * 256 + koel);
            #pragma unroll
            for (int et = 0; et < 4; ++et)
                acc[ht][et] = __builtin_amdgcn_mfma_f32_16x16x32_bf16(afr, bfr[et], acc[ht][et], 0, 0, 0);
        }
    }
    __syncthreads();   // A reads done; alias H

    #pragma unroll
    for (int ht = 0; ht < 2; ++ht) {
        const int h0 = hbase + ht * 16 + l4 * 4;
        float4 bb = *reinterpret_cast<const float4*>(b1 + h0);
        #pragma unroll
        for (int et = 0; et < 4; ++et) {
            int e = et * 16 + l15;
            float x0 = fmaxf(acc[ht][et][0] + bb.x, 0.f);
            float x1 = fmaxf(acc[ht][et][1] + bb.y, 0.f);
            float x2 = fmaxf(acc[ht][et][2] + bb.z, 0.f);
            float x3 = fmaxf(acc[ht][et][3] + bb.w, 0.f);
            uint2 u; u.x = pkbf(x0, x1); u.y = pkbf(x2, x3);
            *reinterpret_cast<uint2*>(&Abuf[swz(e * 512 + h0 * 2, e)]) = u;
        }
    }
    __syncthreads();

    // GEMM2
    f32x4 acc2[4] = {};
    const int cbase = wave * 16;
    #pragma unroll
    for (int kk = 0; kk < 256; kk += 32) {
        const int koel = kk + l4 * 8;
        short8 afr = *reinterpret_cast<const short8*>(
            w2t + (size_t)(cbase + l15) * 256 + koel);
        #pragma unroll
        for (int et = 0; et < 4; ++et) {
            int rw = et * 16 + l15;
            short8 bfr = *reinterpret_cast<const short8*>(&Abuf[swz(rw * 512 + koel * 2, rw)]);
            acc2[et] = __builtin_amdgcn_mfma_f32_16x16x32_bf16(afr, bfr, acc2[et], 0, 0, 0);
        }
    }

    {
        const int c0 = cbase + l4 * 4;
        float4 bb = *reinterpret_cast<const float4*>(b2 + c0);
        #pragma unroll
        for (int et = 0; et < 4; ++et) {
            int nn2 = n0 + et * 16 + l15;
            if (nn2 < NN) {
                float4 v;
                v.x = acc2[et][0] + bb.x;
                v.y = acc2[et][1] + bb.y;
                v.z = acc2[et][2] + bb.z;
                v.w = acc2[et][3] + bb.w;
                *reinterpret_cast<float4*>(out + (size_t)nn2 * RR + c0) = v;
            }
        }
    }
}

extern "C" void kernel_launch(void* const* d_in, const int* in_sizes, int n_in,
                              void* d_out, int out_size, void* d_ws, size_t ws_size,
                              hipStream_t stream) {
    const float* node_rep  = (const float*)d_in[0];
    const float* edge_attr = (const float*)d_in[1];
    const int*   esrc      = (const int*)d_in[2];
    const int*   edst      = (const int*)d_in[3];
    const float* W1e = (const float*)d_in[4];
    const float* b1e = (const float*)d_in[5];
    const float* W2e = (const float*)d_in[6];
    const float* b2e = (const float*)d_in[7];
    const float* W1n = (const float*)d_in[8];
    const float* b1n = (const float*)d_in[9];
    const float* W2n = (const float*)d_in[10];
    const float* b2n = (const float*)d_in[11];

    float* out      = (float*)d_out;
    float* node_out = out;                          // N*R
    float* edge_out = out + (size_t)NN * RR;        // E*R

    // workspace layout
    char* ws = (char*)d_ws;
    unsigned short* w1et = (unsigned short*)ws;                 // [256][384]
    unsigned short* w2et = w1et + 256 * 384;                    // [128][256]
    unsigned short* w1nt = w2et + 128 * 256;                    // [256][256]
    unsigned short* w2nt = w1nt + 256 * 256;                    // [128][256]
    int* cnt  = (int*)(ws + 458752);                            // [NN]  (also fill cursor)
    int* offs = (int*)(ws + 458752 + 400000);                   // [NN+1]
    int* adj  = (int*)(ws + 458752 + 400000 + 400008);          // [2*NE]
    int* bsum = (int*)(ws + 458752 + 400000 + 400008 + 4800000);// [NB_SCAN]

    hipMemsetAsync(cnt, 0, (size_t)NN * sizeof(int), stream);

    transpose_cast<<<(384 * 256 + 255) / 256, 256, 0, stream>>>(W1e, w1et, 384, 256);
    transpose_cast<<<(256 * 128 + 255) / 256, 256, 0, stream>>>(W2e, w2et, 256, 128);
    transpose_cast<<<(256 * 256 + 255) / 256, 256, 0, stream>>>(W1n, w1nt, 256, 256);
    transpose_cast<<<(256 * 128 + 255) / 256, 256, 0, stream>>>(W2n, w2nt, 256, 128);

    count_kernel<<<(NE + 255) / 256, 256, 0, stream>>>(esrc, edst, cnt);
    scan_part<<<NB_SCAN, 1024, 0, stream>>>(cnt, offs, bsum);
    scan_tops<<<1, 64, 0, stream>>>(bsum, offs + NN);
    scan_add<<<NB_SCAN, 1024, 0, stream>>>(offs, bsum, cnt);
    fill_kernel<<<(NE + 255) / 256, 256, 0, stream>>>(esrc, edst, cnt, adj);

    edge_kernel<<<NE / 64, 512, 0, stream>>>(node_rep, edge_attr, esrc, edst,
                                             w1et, b1e, w2et, b2e, edge_out);

    node_kernel<<<(NN + 63) / 64, 512, 0, stream>>>(node_rep, offs, adj, edge_out,
                                                    w1nt, b1n, w2nt, b2n, node_out);
}